// Round 2
// baseline (280.906 us; speedup 1.0000x reference)
//
#include <hip/hip_runtime.h>

// ---------- types ----------
typedef __attribute__((ext_vector_type(8))) short short8;            // 8 bf16
typedef __attribute__((ext_vector_type(4))) unsigned short ushort4v; // 4 bf16
typedef __attribute__((ext_vector_type(4))) float floatx4;           // MFMA acc

// fp32 -> bf16 (RNE)
static __device__ __forceinline__ unsigned short f2bf(float f) {
    unsigned int u = __float_as_uint(f);
    u = (u + 0x7FFFu + ((u >> 16) & 1u)) >> 16;
    return (unsigned short)u;
}

// ---------- kernel 0 (prep): starts + Wt (no table cast anymore) ----------
__global__ __launch_bounds__(256) void prep_kernel(
        const int* __restrict__ seg, int M, int num_cells,
        const float* __restrict__ W,
        int* __restrict__ starts,
        unsigned short* __restrict__ Wt,
        int startB) {
    const int b = blockIdx.x;
    const int tid = threadIdx.x;
    if (b < startB) {
        int m = b * 256 + tid;
        if (m > M) return;
        int prev = (m == 0) ? -1 : seg[m - 1];
        int cur  = (m == M) ? num_cells : seg[m];
        for (int c = prev + 1; c <= cur; ++c) starts[c] = m;
    } else {
        int g = (b - startB) * 256 + tid;   // 0 .. 512*256-1
        if (g < 512 * 256) {
            int n = g >> 8, k = g & 255;
            Wt[g] = f2bf(W[k * 512 + n]);   // Wt[n][k] = W[k][n], bf16
        }
    }
}

// ---------- kernel 1: segment mean, f32 gather -> cell_emb bf16 ----------
// wave-per-cell. One f32 member row = 256 floats = 1 KB = 64 lanes x float4,
// so a single global_load_dwordx4 per lane fetches a whole row; lane owns
// features lane*4..lane*4+3. 8 rows kept in flight. Table (102.4 MB) is
// L3-resident; no bf16 table cast needed. Accumulate in f32 (exact vs ref).
__global__ __launch_bounds__(256) void seg_mean_kernel(
        const float* __restrict__ cf,
        const int* __restrict__ member_idx,
        const int* __restrict__ starts,
        int num_cells,
        unsigned short* __restrict__ cell_emb) {
    const int wid  = threadIdx.x >> 6;
    const int lane = threadIdx.x & 63;
    const int c = blockIdx.x * 4 + wid;

    float acc[4] = {0.f, 0.f, 0.f, 0.f};
    int cnt = 0;

    if (c < num_cells) {
        const int s = starts[c];
        const int e = starts[c + 1];
        cnt = e - s;

        for (int base = s; base < e; base += 64) {
            int m = base + lane;
            int idx = (m < e) ? member_idx[m] : 0;          // coalesced
            int n = e - base; if (n > 64) n = 64;
            for (int j0 = 0; j0 < n; j0 += 8) {             // 8 rows in flight
                float4 v[8];
#pragma unroll
                for (int p = 0; p < 8; ++p) {
                    int j = j0 + p;
                    if (j < n) {
                        int ci = __shfl(idx, j);
                        v[p] = *(const float4*)(cf + (size_t)ci * 256 + lane * 4);
                    }
                }
#pragma unroll
                for (int p = 0; p < 8; ++p) {
                    int j = j0 + p;
                    if (j < n) {
                        acc[0] += v[p].x; acc[1] += v[p].y;
                        acc[2] += v[p].z; acc[3] += v[p].w;
                    }
                }
            }
        }
    }

    // scale + store (all waves store; padding rows [num_cells, Mpad) get zeros)
    float inv = (cnt > 0) ? 1.0f / (float)cnt : 0.f;
    ushort4v o;
#pragma unroll
    for (int t = 0; t < 4; ++t) o[t] = f2bf(acc[t] * inv);
    *(ushort4v*)(cell_emb + (size_t)c * 256 + lane * 4) = o;
}

// ---------- kernel 2: C[Mpad x 512] = A[Mpad x 256] * W[256 x 512] + b ----------
__global__ __launch_bounds__(256) void gemm_kernel(
        const unsigned short* __restrict__ A,
        const unsigned short* __restrict__ Bt,
        const float* __restrict__ bias,
        float* __restrict__ out,
        int Mreal) {
    constexpr int LDSS = 40;             // padded stride (bf16 elems)
    __shared__ unsigned short As[128 * LDSS];
    __shared__ unsigned short Bs[128 * LDSS];

    const int tid  = threadIdx.x;
    const int wid  = tid >> 6;
    const int lane = tid & 63;
    const int wm = wid & 1, wn = wid >> 1;
    const int l15 = lane & 15, q = lane >> 4;
    const int m0 = blockIdx.y * 128;
    const int n0 = blockIdx.x * 128;

    floatx4 acc[4][4] = {};

    for (int kb = 0; kb < 256; kb += 32) {
#pragma unroll
        for (int r = 0; r < 2; ++r) {
            int chunk = tid + r * 256;          // 0..511
            int row = chunk >> 2;               // 0..127
            int col = (chunk & 3) * 8;          // 0,8,16,24
            *(short8*)&As[row * LDSS + col] =
                *(const short8*)&A[(size_t)(m0 + row) * 256 + kb + col];
            *(short8*)&Bs[row * LDSS + col] =
                *(const short8*)&Bt[(size_t)(n0 + row) * 256 + kb + col];
        }
        __syncthreads();

        short8 af[4], bf[4];
#pragma unroll
        for (int mi = 0; mi < 4; ++mi)
            af[mi] = *(const short8*)&As[(wm * 64 + mi * 16 + l15) * LDSS + q * 8];
#pragma unroll
        for (int ni = 0; ni < 4; ++ni)
            bf[ni] = *(const short8*)&Bs[(wn * 64 + ni * 16 + l15) * LDSS + q * 8];
#pragma unroll
        for (int mi = 0; mi < 4; ++mi)
#pragma unroll
            for (int ni = 0; ni < 4; ++ni)
                acc[mi][ni] = __builtin_amdgcn_mfma_f32_16x16x32_bf16(
                    af[mi], bf[ni], acc[mi][ni], 0, 0, 0);
        __syncthreads();
    }

#pragma unroll
    for (int ni = 0; ni < 4; ++ni) {
        int n = n0 + wn * 64 + ni * 16 + l15;
        float bv = bias[n];
#pragma unroll
        for (int mi = 0; mi < 4; ++mi) {
            int mbase = m0 + wm * 64 + mi * 16 + q * 4;
#pragma unroll
            for (int r = 0; r < 4; ++r) {
                int row = mbase + r;
                if (row < Mreal)
                    out[(size_t)row * 512 + n] = acc[mi][ni][r] + bv;
            }
        }
    }
}

extern "C" void kernel_launch(void* const* d_in, const int* in_sizes, int n_in,
                              void* d_out, int out_size, void* d_ws, size_t ws_size,
                              hipStream_t stream) {
    const float* chunk_features = (const float*)d_in[0];
    const int*   member_idx     = (const int*)d_in[1];
    const int*   segment_ids    = (const int*)d_in[2];
    const float* W              = (const float*)d_in[4];
    const float* bias           = (const float*)d_in[5];
    float* out = (float*)d_out;

    const int M          = in_sizes[1];          // 400000 members
    const int out_dim    = in_sizes[5];          // 512
    const int num_cells  = out_size / out_dim;   // 50000
    const int mtiles = (num_cells + 127) / 128;  // 391
    const int Mpad   = mtiles * 128;             // 50048

    unsigned short* cell_emb = (unsigned short*)d_ws;                 // Mpad*256 bf16
    unsigned short* Wt       = cell_emb + (size_t)Mpad * 256;         // 512*256 bf16
    int*            starts   = (int*)(Wt + 512 * 256);                // num_cells+1

    const int startB = (M + 1 + 255) / 256;
    const int wtB    = (512 * 256 + 255) / 256;

    hipLaunchKernelGGL(prep_kernel, dim3(startB + wtB), dim3(256), 0, stream,
                       segment_ids, M, num_cells, W, starts, Wt, startB);
    hipLaunchKernelGGL(seg_mean_kernel, dim3(Mpad / 4), dim3(256), 0, stream,
                       chunk_features, member_idx, starts, num_cells, cell_emb);
    hipLaunchKernelGGL(gemm_kernel, dim3(4, mtiles), dim3(256), 0, stream,
                       cell_emb, Wt, bias, out, num_cells);
}

// Round 3
// 278.437 us; speedup vs baseline: 1.0089x; 1.0089x over previous
//
#include <hip/hip_runtime.h>

// ---------- types ----------
typedef __attribute__((ext_vector_type(8))) short short8;            // 8 bf16
typedef __attribute__((ext_vector_type(4))) unsigned short ushort4v; // 4 bf16
typedef __attribute__((ext_vector_type(4))) float floatx4;           // MFMA acc

// fp32 -> bf16 (RNE)
static __device__ __forceinline__ unsigned short f2bf(float f) {
    unsigned int u = __float_as_uint(f);
    u = (u + 0x7FFFu + ((u >> 16) & 1u)) >> 16;
    return (unsigned short)u;
}
static __device__ __forceinline__ float bf2f(unsigned short h) {
    return __uint_as_float(((unsigned int)h) << 16);
}

// ---------- kernel 0 (fused prep): cast table + starts + Wt ----------
// Cast is HBM-streaming (154 MB ~ 24 us) and buys a 2x cut in seg_mean's
// random-gather bytes (fabric-BW-bound at ~3 TB/s).
__global__ __launch_bounds__(256) void prep_kernel(
        const float* __restrict__ cf, int cast_elems,
        const int* __restrict__ seg, int M, int num_cells,
        const float* __restrict__ W,
        unsigned short* __restrict__ cf16,
        int* __restrict__ starts,
        unsigned short* __restrict__ Wt,
        int castB, int startB) {
    const int b = blockIdx.x;
    const int tid = threadIdx.x;
    if (b < castB) {
        int g = (b * 256 + tid) * 8;
        if (g + 8 <= cast_elems) {
            float4 a = *(const float4*)(cf + g);
            float4 c = *(const float4*)(cf + g + 4);
            short8 o;
            o[0] = (short)f2bf(a.x); o[1] = (short)f2bf(a.y);
            o[2] = (short)f2bf(a.z); o[3] = (short)f2bf(a.w);
            o[4] = (short)f2bf(c.x); o[5] = (short)f2bf(c.y);
            o[6] = (short)f2bf(c.z); o[7] = (short)f2bf(c.w);
            *(short8*)(cf16 + g) = o;
        } else {
            for (int i = g; i < cast_elems; ++i) cf16[i] = f2bf(cf[i]);
        }
    } else if (b < castB + startB) {
        int m = (b - castB) * 256 + tid;
        if (m > M) return;
        int prev = (m == 0) ? -1 : seg[m - 1];
        int cur  = (m == M) ? num_cells : seg[m];
        for (int c = prev + 1; c <= cur; ++c) starts[c] = m;
    } else {
        int g = (b - castB - startB) * 256 + tid;   // 0 .. 512*256-1
        if (g < 512 * 256) {
            int n = g >> 8, k = g & 255;
            Wt[g] = f2bf(W[k * 512 + n]);           // Wt[n][k] = W[k][n]
        }
    }
}

// ---------- kernel 1: segment mean over bf16 table -> cell_emb bf16 ----------
// wave-per-cell. One bf16 row = 256 bf16 = 512 B = 64 lanes x dwordx2, so one
// wave-load fetches a whole member row; lane owns features lane*4..lane*4+3.
// 16 rows in flight (8 KB/lane-batch in flight, same as round-2's 8x1KB).
// f32 accumulate.
__global__ __launch_bounds__(256) void seg_mean_kernel(
        const unsigned short* __restrict__ cf16,
        const int* __restrict__ member_idx,
        const int* __restrict__ starts,
        int num_cells,
        unsigned short* __restrict__ cell_emb) {
    const int wid  = threadIdx.x >> 6;
    const int lane = threadIdx.x & 63;
    const int c = blockIdx.x * 4 + wid;

    float acc[4] = {0.f, 0.f, 0.f, 0.f};
    int cnt = 0;

    if (c < num_cells) {
        const int s = starts[c];
        const int e = starts[c + 1];
        cnt = e - s;

        for (int base = s; base < e; base += 64) {
            int m = base + lane;
            int idx = (m < e) ? member_idx[m] : 0;          // coalesced
            int n = e - base; if (n > 64) n = 64;
            for (int j0 = 0; j0 < n; j0 += 16) {            // 16 rows in flight
                ushort4v v[16];
#pragma unroll
                for (int p = 0; p < 16; ++p) {
                    int j = j0 + p;
                    if (j < n) {
                        int ci = __shfl(idx, j);
                        v[p] = *(const ushort4v*)(cf16 + (size_t)ci * 256 + lane * 4);
                    }
                }
#pragma unroll
                for (int p = 0; p < 16; ++p) {
                    int j = j0 + p;
                    if (j < n) {
                        acc[0] += bf2f(v[p][0]); acc[1] += bf2f(v[p][1]);
                        acc[2] += bf2f(v[p][2]); acc[3] += bf2f(v[p][3]);
                    }
                }
            }
        }
    }

    // scale + store (padding rows [num_cells, Mpad) get zeros)
    float inv = (cnt > 0) ? 1.0f / (float)cnt : 0.f;
    ushort4v o;
#pragma unroll
    for (int t = 0; t < 4; ++t) o[t] = f2bf(acc[t] * inv);
    *(ushort4v*)(cell_emb + (size_t)c * 256 + lane * 4) = o;
}

// ---------- kernel 2: C[Mpad x 512] = A[Mpad x 256] * W[256 x 512] + b ----------
__global__ __launch_bounds__(256) void gemm_kernel(
        const unsigned short* __restrict__ A,
        const unsigned short* __restrict__ Bt,
        const float* __restrict__ bias,
        float* __restrict__ out,
        int Mreal) {
    constexpr int LDSS = 40;             // padded stride (bf16 elems)
    __shared__ unsigned short As[128 * LDSS];
    __shared__ unsigned short Bs[128 * LDSS];

    const int tid  = threadIdx.x;
    const int wid  = tid >> 6;
    const int lane = tid & 63;
    const int wm = wid & 1, wn = wid >> 1;
    const int l15 = lane & 15, q = lane >> 4;
    const int m0 = blockIdx.y * 128;
    const int n0 = blockIdx.x * 128;

    floatx4 acc[4][4] = {};

    for (int kb = 0; kb < 256; kb += 32) {
#pragma unroll
        for (int r = 0; r < 2; ++r) {
            int chunk = tid + r * 256;          // 0..511
            int row = chunk >> 2;               // 0..127
            int col = (chunk & 3) * 8;          // 0,8,16,24
            *(short8*)&As[row * LDSS + col] =
                *(const short8*)&A[(size_t)(m0 + row) * 256 + kb + col];
            *(short8*)&Bs[row * LDSS + col] =
                *(const short8*)&Bt[(size_t)(n0 + row) * 256 + kb + col];
        }
        __syncthreads();

        short8 af[4], bf[4];
#pragma unroll
        for (int mi = 0; mi < 4; ++mi)
            af[mi] = *(const short8*)&As[(wm * 64 + mi * 16 + l15) * LDSS + q * 8];
#pragma unroll
        for (int ni = 0; ni < 4; ++ni)
            bf[ni] = *(const short8*)&Bs[(wn * 64 + ni * 16 + l15) * LDSS + q * 8];
#pragma unroll
        for (int mi = 0; mi < 4; ++mi)
#pragma unroll
            for (int ni = 0; ni < 4; ++ni)
                acc[mi][ni] = __builtin_amdgcn_mfma_f32_16x16x32_bf16(
                    af[mi], bf[ni], acc[mi][ni], 0, 0, 0);
        __syncthreads();
    }

#pragma unroll
    for (int ni = 0; ni < 4; ++ni) {
        int n = n0 + wn * 64 + ni * 16 + l15;
        float bv = bias[n];
#pragma unroll
        for (int mi = 0; mi < 4; ++mi) {
            int mbase = m0 + wm * 64 + mi * 16 + q * 4;
#pragma unroll
            for (int r = 0; r < 4; ++r) {
                int row = mbase + r;
                if (row < Mreal)
                    out[(size_t)row * 512 + n] = acc[mi][ni][r] + bv;
            }
        }
    }
}

extern "C" void kernel_launch(void* const* d_in, const int* in_sizes, int n_in,
                              void* d_out, int out_size, void* d_ws, size_t ws_size,
                              hipStream_t stream) {
    const float* chunk_features = (const float*)d_in[0];
    const int*   member_idx     = (const int*)d_in[1];
    const int*   segment_ids    = (const int*)d_in[2];
    const float* W              = (const float*)d_in[4];
    const float* bias           = (const float*)d_in[5];
    float* out = (float*)d_out;

    const int cast_elems = in_sizes[0];          // 100000*256 = 25.6M
    const int M          = in_sizes[1];          // 400000 members
    const int out_dim    = in_sizes[5];          // 512
    const int num_cells  = out_size / out_dim;   // 50000
    const int mtiles = (num_cells + 127) / 128;  // 391
    const int Mpad   = mtiles * 128;             // 50048

    unsigned short* cell_emb = (unsigned short*)d_ws;                 // Mpad*256 bf16
    unsigned short* Wt       = cell_emb + (size_t)Mpad * 256;         // 512*256 bf16
    unsigned short* cf16     = Wt + 512 * 256;                        // cast_elems bf16
    int*            starts   = (int*)(cf16 + (((size_t)cast_elems + 7) & ~7ull)); // num_cells+1

    const int castB  = (cast_elems + 2047) / 2048;   // 8 elems/thread
    const int startB = (M + 1 + 255) / 256;
    const int wtB    = (512 * 256 + 255) / 256;

    hipLaunchKernelGGL(prep_kernel, dim3(castB + startB + wtB), dim3(256), 0, stream,
                       chunk_features, cast_elems, segment_ids, M, num_cells, W,
                       cf16, starts, Wt, castB, startB);
    hipLaunchKernelGGL(seg_mean_kernel, dim3(Mpad / 4), dim3(256), 0, stream,
                       cf16, member_idx, starts, num_cells, cell_emb);
    hipLaunchKernelGGL(gemm_kernel, dim3(4, mtiles), dim3(256), 0, stream,
                       cell_emb, Wt, bias, out, num_cells);
}

// Round 5
// 261.686 us; speedup vs baseline: 1.0734x; 1.0640x over previous
//
#include <hip/hip_runtime.h>

// ---------- types ----------
typedef __attribute__((ext_vector_type(8))) short short8;            // 8 bf16
typedef __attribute__((ext_vector_type(4))) unsigned short ushort4v; // 4 bf16
typedef __attribute__((ext_vector_type(4))) float floatx4;           // MFMA acc

// fp32 -> bf16 (RNE)
static __device__ __forceinline__ unsigned short f2bf(float f) {
    unsigned int u = __float_as_uint(f);
    u = (u + 0x7FFFu + ((u >> 16) & 1u)) >> 16;
    return (unsigned short)u;
}

// ---------- kernel 0 (prep): starts + Wt (no table cast) ----------
__global__ __launch_bounds__(256) void prep_kernel(
        const int* __restrict__ seg, int M, int num_cells,
        const float* __restrict__ W,
        int* __restrict__ starts,
        unsigned short* __restrict__ Wt,
        int startB) {
    const int b = blockIdx.x;
    const int tid = threadIdx.x;
    if (b < startB) {
        int m = b * 256 + tid;
        if (m > M) return;
        int prev = (m == 0) ? -1 : seg[m - 1];
        int cur  = (m == M) ? num_cells : seg[m];
        for (int c = prev + 1; c <= cur; ++c) starts[c] = m;
    } else {
        int g = (b - startB) * 256 + tid;   // 0 .. 512*256-1
        if (g < 512 * 256) {
            int n = g >> 8, k = g & 255;
            Wt[g] = f2bf(W[k * 512 + n]);   // Wt[n][k] = W[k][n], bf16
        }
    }
}

// ---------- kernel 1: segment mean, f32 gather -> cell_emb bf16 ----------
// wave-per-cell. One f32 member row = 256 floats = 1 KB = 64 lanes x float4,
// so a single global_load_dwordx4 per lane fetches a whole row; lane owns
// features lane*4..lane*4+3. 8 rows kept in flight. Table (102.4 MB) is
// L3-resident; no bf16 table cast needed. Accumulate in f32 (exact vs ref).
__global__ __launch_bounds__(256) void seg_mean_kernel(
        const float* __restrict__ cf,
        const int* __restrict__ member_idx,
        const int* __restrict__ starts,
        int num_cells,
        unsigned short* __restrict__ cell_emb) {
    const int wid  = threadIdx.x >> 6;
    const int lane = threadIdx.x & 63;
    const int c = blockIdx.x * 4 + wid;

    float acc[4] = {0.f, 0.f, 0.f, 0.f};
    int cnt = 0;

    if (c < num_cells) {
        const int s = starts[c];
        const int e = starts[c + 1];
        cnt = e - s;

        for (int base = s; base < e; base += 64) {
            int m = base + lane;
            int idx = (m < e) ? member_idx[m] : 0;          // coalesced
            int n = e - base; if (n > 64) n = 64;
            for (int j0 = 0; j0 < n; j0 += 8) {             // 8 rows in flight
                float4 v[8];
#pragma unroll
                for (int p = 0; p < 8; ++p) {
                    int j = j0 + p;
                    if (j < n) {
                        int ci = __shfl(idx, j);
                        v[p] = *(const float4*)(cf + (size_t)ci * 256 + lane * 4);
                    }
                }
#pragma unroll
                for (int p = 0; p < 8; ++p) {
                    int j = j0 + p;
                    if (j < n) {
                        acc[0] += v[p].x; acc[1] += v[p].y;
                        acc[2] += v[p].z; acc[3] += v[p].w;
                    }
                }
            }
        }
    }

    // scale + store (all waves store; padding rows [num_cells, Mpad) get zeros)
    float inv = (cnt > 0) ? 1.0f / (float)cnt : 0.f;
    ushort4v o;
#pragma unroll
    for (int t = 0; t < 4; ++t) o[t] = f2bf(acc[t] * inv);
    *(ushort4v*)(cell_emb + (size_t)c * 256 + lane * 4) = o;
}

// ---------- kernel 2: C[Mpad x 512] = A[Mpad x 256] * W[256 x 512] + b ----------
__global__ __launch_bounds__(256) void gemm_kernel(
        const unsigned short* __restrict__ A,
        const unsigned short* __restrict__ Bt,
        const float* __restrict__ bias,
        float* __restrict__ out,
        int Mreal) {
    constexpr int LDSS = 40;             // padded stride (bf16 elems)
    __shared__ unsigned short As[128 * LDSS];
    __shared__ unsigned short Bs[128 * LDSS];

    const int tid  = threadIdx.x;
    const int wid  = tid >> 6;
    const int lane = tid & 63;
    const int wm = wid & 1, wn = wid >> 1;
    const int l15 = lane & 15, q = lane >> 4;
    const int m0 = blockIdx.y * 128;
    const int n0 = blockIdx.x * 128;

    floatx4 acc[4][4] = {};

    for (int kb = 0; kb < 256; kb += 32) {
#pragma unroll
        for (int r = 0; r < 2; ++r) {
            int chunk = tid + r * 256;          // 0..511
            int row = chunk >> 2;               // 0..127
            int col = (chunk & 3) * 8;          // 0,8,16,24
            *(short8*)&As[row * LDSS + col] =
                *(const short8*)&A[(size_t)(m0 + row) * 256 + kb + col];
            *(short8*)&Bs[row * LDSS + col] =
                *(const short8*)&Bt[(size_t)(n0 + row) * 256 + kb + col];
        }
        __syncthreads();

        short8 af[4], bf[4];
#pragma unroll
        for (int mi = 0; mi < 4; ++mi)
            af[mi] = *(const short8*)&As[(wm * 64 + mi * 16 + l15) * LDSS + q * 8];
#pragma unroll
        for (int ni = 0; ni < 4; ++ni)
            bf[ni] = *(const short8*)&Bs[(wn * 64 + ni * 16 + l15) * LDSS + q * 8];
#pragma unroll
        for (int mi = 0; mi < 4; ++mi)
#pragma unroll
            for (int ni = 0; ni < 4; ++ni)
                acc[mi][ni] = __builtin_amdgcn_mfma_f32_16x16x32_bf16(
                    af[mi], bf[ni], acc[mi][ni], 0, 0, 0);
        __syncthreads();
    }

#pragma unroll
    for (int ni = 0; ni < 4; ++ni) {
        int n = n0 + wn * 64 + ni * 16 + l15;
        float bv = bias[n];
#pragma unroll
        for (int mi = 0; mi < 4; ++mi) {
            int mbase = m0 + wm * 64 + mi * 16 + q * 4;
#pragma unroll
            for (int r = 0; r < 4; ++r) {
                int row = mbase + r;
                if (row < Mreal)
                    out[(size_t)row * 512 + n] = acc[mi][ni][r] + bv;
            }
        }
    }
}

extern "C" void kernel_launch(void* const* d_in, const int* in_sizes, int n_in,
                              void* d_out, int out_size, void* d_ws, size_t ws_size,
                              hipStream_t stream) {
    const float* chunk_features = (const float*)d_in[0];
    const int*   member_idx     = (const int*)d_in[1];
    const int*   segment_ids    = (const int*)d_in[2];
    const float* W              = (const float*)d_in[4];
    const float* bias           = (const float*)d_in[5];
    float* out = (float*)d_out;

    const int M          = in_sizes[1];          // 400000 members
    const int out_dim    = in_sizes[5];          // 512
    const int num_cells  = out_size / out_dim;   // 50000
    const int mtiles = (num_cells + 127) / 128;  // 391
    const int Mpad   = mtiles * 128;             // 50048

    unsigned short* cell_emb = (unsigned short*)d_ws;                 // Mpad*256 bf16
    unsigned short* Wt       = cell_emb + (size_t)Mpad * 256;         // 512*256 bf16
    int*            starts   = (int*)(Wt + 512 * 256);                // num_cells+1

    const int startB = (M + 1 + 255) / 256;
    const int wtB    = (512 * 256 + 255) / 256;

    hipLaunchKernelGGL(prep_kernel, dim3(startB + wtB), dim3(256), 0, stream,
                       segment_ids, M, num_cells, W, starts, Wt, startB);
    hipLaunchKernelGGL(seg_mean_kernel, dim3(Mpad / 4), dim3(256), 0, stream,
                       chunk_features, member_idx, starts, num_cells, cell_emb);
    hipLaunchKernelGGL(gemm_kernel, dim3(4, mtiles), dim3(256), 0, stream,
                       cell_emb, Wt, bias, out, num_cells);
}